// Round 9
// baseline (245.048 us; speedup 1.0000x reference)
//
#include <hip/hip_runtime.h>
#include <math.h>

#define BB   16
#define SS   4096
#define DD   64
#define HH   8
#define NBH  32
#define NB   64
#define NCH  512     // global chunks per batch = HH * 64

typedef __attribute__((ext_vector_type(8))) short s16x8;   // 8 bf16
typedef __attribute__((ext_vector_type(4))) short s16x4;   // 4 bf16
typedef __attribute__((ext_vector_type(4))) float f32x4;

static __device__ __forceinline__ unsigned short f2bf(float x) {
  union { float f; unsigned u; } a; a.f = x;
  unsigned r = a.u + 0x7fffu + ((a.u >> 16) & 1u);   // RNE
  return (unsigned short)(r >> 16);
}
static __device__ __forceinline__ float bf2f(unsigned short u) {
  union { unsigned u; float f; } a; a.u = ((unsigned)u) << 16;
  return a.f;
}

// ---------------------------------------------------------------------------
// Kernel 0: streaming fp32->bf16 conversion (R7, unchanged).
// ---------------------------------------------------------------------------
__global__ __launch_bounds__(256) void k_conv(
    const float* __restrict__ qk, const float* __restrict__ v,
    unsigned short* __restrict__ qb, unsigned short* __restrict__ kb,
    unsigned short* __restrict__ vb) {
  const int gid = blockIdx.x * 256 + threadIdx.x;
  const int half = BB * SS * 4;
  const bool isV = gid >= half;
  const int id = isV ? gid - half : gid;
  const int row = id >> 2, q4 = id & 3;

  const float4* src =
      (const float4*)((isV ? v : qk) + (size_t)row * DD + q4 * 16);
  float vals[16];
#pragma unroll
  for (int g = 0; g < 4; g++) {
    const float4 a = src[g];
    vals[g * 4 + 0] = a.x; vals[g * 4 + 1] = a.y;
    vals[g * 4 + 2] = a.z; vals[g * 4 + 3] = a.w;
  }

  if (!isV) {
    float ss = 0.f;
#pragma unroll
    for (int i = 0; i < 16; i++) ss += vals[i] * vals[i];
    ss += __shfl_xor(ss, 1);
    ss += __shfl_xor(ss, 2);
    const float scl = 0.125f / (sqrtf(ss) + 1e-6f);
    unsigned short qo[16], ko[16];
#pragma unroll
    for (int i = 0; i < 16; i++) {
      qo[i] = f2bf(vals[i]);
      ko[i] = f2bf(vals[i] * scl);
    }
    unsigned short* qd = qb + (size_t)row * DD + q4 * 16;
    unsigned short* kd = kb + (size_t)row * DD + q4 * 16;
    *(s16x8*)qd = *(const s16x8*)&qo[0];
    *(s16x8*)(qd + 8) = *(const s16x8*)&qo[8];
    *(s16x8*)kd = *(const s16x8*)&ko[0];
    *(s16x8*)(kd + 8) = *(const s16x8*)&ko[8];
  } else {
    unsigned short vo[16];
#pragma unroll
    for (int i = 0; i < 16; i++) vo[i] = f2bf(vals[i]);
    unsigned short* vd = vb + (size_t)row * DD + q4 * 16;
    *(s16x8*)vd = *(const s16x8*)&vo[0];
    *(s16x8*)(vd + 8) = *(const s16x8*)&vo[8];
  }
}

// ---------------------------------------------------------------------------
// Kernel 0b: transpose rotations to rT[b][h][i][f], split hi/lo bf16.
// Block = b; thread = (h,i); two 32-f stages through LDS (32 KB).
// ---------------------------------------------------------------------------
__global__ __launch_bounds__(256) void k_rotT(
    const float* __restrict__ rot, unsigned short* __restrict__ rTh,
    unsigned short* __restrict__ rTl) {
  __shared__ float slab[32][256];
  const int b = blockIdx.x;
  const int tid = threadIdx.x;

  for (int st = 0; st < 2; st++) {
    // coalesced read: rot[b][f][h][i], linear idx = f*256 + (h*32+i)
#pragma unroll
    for (int fr = 0; fr < 32; fr++)
      slab[fr][tid] = rot[(size_t)b * (DD * 256 / 4) * 4 +
                          (size_t)(st * 32 + fr) * 256 + tid];
    __syncthreads();
    unsigned short hi[32], lo[32];
#pragma unroll
    for (int fr = 0; fr < 32; fr++) {
      const float x = slab[fr][tid];
      const unsigned short hh = f2bf(x);
      hi[fr] = hh;
      lo[fr] = f2bf(x - bf2f(hh));
    }
    unsigned short* dh = rTh + ((size_t)b * 256 + tid) * DD + st * 32;
    unsigned short* dl = rTl + ((size_t)b * 256 + tid) * DD + st * 32;
#pragma unroll
    for (int g = 0; g < 4; g++) {
      *(s16x8*)(dh + g * 8) = *(const s16x8*)&hi[g * 8];
      *(s16x8*)(dl + g * 8) = *(const s16x8*)&lo[g * 8];
    }
    __syncthreads();
  }
}

// ---------------------------------------------------------------------------
// Kernel 1a: MFMA LSH hash. Block = (b, 128-token tile); wave w owns m-tiles
// {2w, 2w+1}; loops all 8 h. A = qk split hi/lo (LDS), B = rT split hi/lo
// (global b128). acc = AhBh+AhBl+AlBh+AlBl -> |err| <~ 1e-3 << MARGIN, so
// non-needy tokens provably equal the exact-fp64 argmax (same invariant as
// R5-R8's fp32 path); needy go to k_hash_fix. Buckets bit-identical
// (absmax 10.0 vs np is a fixed near-tie; do not perturb MARGIN/logic).
// Argmax scan is ascending i with strict > : np first-max semantics.
// ---------------------------------------------------------------------------
#define MARGIN 1e-2f

__global__ __launch_bounds__(256, 2) void k_hash_mfma(
    const float* __restrict__ qk, const unsigned short* __restrict__ rTh,
    const unsigned short* __restrict__ rTl, int* __restrict__ bucket_local,
    float* __restrict__ buckets_out, int* __restrict__ needy_list,
    int* __restrict__ needy_count) {
  __shared__ struct __align__(16) {
    unsigned short ah[128][72];   // 18432 B
    unsigned short al[128][72];   // 18432 B
    float sc[128][33];            // 16896 B  -> total 53760
  } sm;
  const int b = blockIdx.x;
  const int t0 = blockIdx.y * 128;
  const int tid = threadIdx.x;
  const int w = tid >> 6, lane = tid & 63;
  const int quad = lane >> 4, l16 = lane & 15;

  // ---- stage A hi/lo (thread = half a token row) ----
  {
    const int row = tid >> 1, hf = tid & 1;
    const float4* src =
        (const float4*)(qk + ((size_t)b * SS + t0 + row) * DD + hf * 32);
    unsigned short hi[32], lo[32];
#pragma unroll
    for (int g = 0; g < 8; g++) {
      const float4 vv = src[g];
      const float a[4] = {vv.x, vv.y, vv.z, vv.w};
#pragma unroll
      for (int e = 0; e < 4; e++) {
        const unsigned short hh = f2bf(a[e]);
        hi[g * 4 + e] = hh;
        lo[g * 4 + e] = f2bf(a[e] - bf2f(hh));
      }
    }
#pragma unroll
    for (int g = 0; g < 4; g++) {
      *(s16x8*)&sm.ah[row][hf * 32 + g * 8] = *(const s16x8*)&hi[g * 8];
      *(s16x8*)&sm.al[row][hf * 32 + g * 8] = *(const s16x8*)&lo[g * 8];
    }
  }
  __syncthreads();

  // ---- hoist A-frags (independent of h) ----
  s16x8 Ah[2][2], Al[2][2];
#pragma unroll
  for (int mtl = 0; mtl < 2; mtl++) {
    const int row = (w * 2 + mtl) * 16 + l16;
#pragma unroll
    for (int ks = 0; ks < 2; ks++) {
      Ah[mtl][ks] = *(const s16x8*)&sm.ah[row][ks * 32 + quad * 8];
      Al[mtl][ks] = *(const s16x8*)&sm.al[row][ks * 32 + quad * 8];
    }
  }

  for (int h = 0; h < HH; h++) {
    // ---- B-frags from global rT (b128 per lane) ----
    s16x8 Bh[2][2], Bl[2][2];
#pragma unroll
    for (int nt = 0; nt < 2; nt++) {
      const size_t rrow =
          (((size_t)b * HH + h) * 32 + nt * 16 + l16) * DD;
#pragma unroll
      for (int ks = 0; ks < 2; ks++) {
        Bh[nt][ks] = *(const s16x8*)&rTh[rrow + ks * 32 + quad * 8];
        Bl[nt][ks] = *(const s16x8*)&rTl[rrow + ks * 32 + quad * 8];
      }
    }
    // ---- MFMA + write scores to LDS ----
#pragma unroll
    for (int mtl = 0; mtl < 2; mtl++) {
#pragma unroll
      for (int nt = 0; nt < 2; nt++) {
        f32x4 acc = (f32x4){0.f, 0.f, 0.f, 0.f};
#pragma unroll
        for (int ks = 0; ks < 2; ks++) {
          acc = __builtin_amdgcn_mfma_f32_16x16x32_bf16(Al[mtl][ks], Bl[nt][ks], acc, 0, 0, 0);
          acc = __builtin_amdgcn_mfma_f32_16x16x32_bf16(Al[mtl][ks], Bh[nt][ks], acc, 0, 0, 0);
          acc = __builtin_amdgcn_mfma_f32_16x16x32_bf16(Ah[mtl][ks], Bl[nt][ks], acc, 0, 0, 0);
          acc = __builtin_amdgcn_mfma_f32_16x16x32_bf16(Ah[mtl][ks], Bh[nt][ks], acc, 0, 0, 0);
        }
#pragma unroll
        for (int r = 0; r < 4; r++)
          sm.sc[(w * 2 + mtl) * 16 + quad * 4 + r][nt * 16 + l16] = acc[r];
      }
    }
    __syncthreads();

    // ---- per-token argmax scan (lanes 0-31 of each wave; wave-local rows) ----
    if (lane < 32) {
      const int tloc = w * 32 + lane;
      float best = -3.0e38f, second = -3.0e38f;
      int bi = 0;
#pragma unroll 8
      for (int i = 0; i < 32; i++) {
        const float vv = sm.sc[tloc][i];
        if (vv > best) { second = best; best = vv; bi = i; }
        else if (vv > second) second = vv;
      }
#pragma unroll 8
      for (int i = 32; i < 64; i++) {
        const float vv = -sm.sc[tloc][i - 32];
        if (vv > best) { second = best; best = vv; bi = i; }
        else if (vv > second) second = vv;
      }
      const int t = t0 + tloc;
      bucket_local[((size_t)b * HH + h) * SS + t] = bi;
      buckets_out[(size_t)b * (HH * SS) + (size_t)h * SS + t] =
          (float)(h * NB + bi);
      if (best - second <= MARGIN) {
        const int slot = atomicAdd(needy_count, 1);
        needy_list[slot] = (((b << 3) | h) << 12) | t;
      }
    }
    __syncthreads();
  }
}

// ---------------------------------------------------------------------------
// Kernel 1b: exact fp64 recompute for near-ties (R6, unchanged).
// ---------------------------------------------------------------------------
__global__ __launch_bounds__(256) void k_hash_fix(
    const float* __restrict__ qk, const float* __restrict__ rot,
    const int* __restrict__ needy_list, const int* __restrict__ needy_count,
    int* __restrict__ bucket_local, float* __restrict__ buckets_out) {
  const int n = *needy_count;
  const int hw = (blockIdx.x * 256 + (int)threadIdx.x) >> 5;
  const int li = threadIdx.x & 31;
  const int nhw = gridDim.x * 8;

  for (int idx = hw; idx < n; idx += nhw) {
    const int code = needy_list[idx];
    const int t = code & 4095;
    const int bh = code >> 12;
    const int b = bh >> 3, h = bh & 7;

    const float* qrow = qk + ((size_t)b * SS + t) * DD;
    const float* rcol = rot + ((size_t)b * DD * HH + h) * NBH + li;

    double acc = 0.0;
#pragma unroll 8
    for (int f = 0; f < DD; f++)
      acc += (double)qrow[f] * (double)rcol[(size_t)f * (HH * NBH)];

    double bv = acc;
    int bi = li;
    if (-acc > bv) { bv = -acc; bi = li + 32; }
#pragma unroll
    for (int off = 1; off < 32; off <<= 1) {
      const double ov = __shfl_xor(bv, off);
      const int oi = __shfl_xor(bi, off);
      if (ov > bv || (ov == bv && oi < bi)) { bv = ov; bi = oi; }
    }
    if (li == 0) {
      bucket_local[((size_t)b * HH + h) * SS + t] = bi;
      buckets_out[(size_t)b * (HH * SS) + (size_t)h * SS + t] =
          (float)(h * NB + bi);
    }
  }
}

// ---------------------------------------------------------------------------
// Kernel 2: parallel stable counting-rank sort per (b,h) (R6, unchanged).
// ---------------------------------------------------------------------------
__global__ __launch_bounds__(256) void k_sort(
    const int* __restrict__ bucket_local, int* __restrict__ sort_t,
    int* __restrict__ ipos) {
  __shared__ unsigned short lb[SS];
  __shared__ unsigned char  cnt[NB][256];
  __shared__ unsigned short pfx[NB][256];
  __shared__ int part[NB][4];
  __shared__ int tot[NB];
  __shared__ int base[NB];

  const int bh = blockIdx.x;
  const int tid = threadIdx.x;
  const int* src = bucket_local + (size_t)bh * SS;

  int* czero = (int*)&cnt[0][0];
#pragma unroll
  for (int i = 0; i < 16; i++) czero[tid + i * 256] = 0;
  __syncthreads();

#pragma unroll
  for (int i = 0; i < 16; i++) {
    const int t = tid * 16 + i;
    const int v = src[t];
    lb[t] = (unsigned short)v;
    cnt[v][tid]++;
  }
  __syncthreads();

  {
    const int bk = tid & 63, sg = tid >> 6;
    int s = 0;
#pragma unroll 8
    for (int i = 0; i < 64; i++) s += cnt[bk][sg * 64 + i];
    part[bk][sg] = s;
  }
  __syncthreads();
  if (tid < NB) tot[tid] = part[tid][0] + part[tid][1] + part[tid][2] + part[tid][3];
  __syncthreads();
  if (tid == 0) {
    int r = 0;
    for (int i = 0; i < NB; i++) { base[i] = r; r += tot[i]; }
  }
  __syncthreads();
  {
    const int bk = tid & 63, sg = tid >> 6;
    int run = base[bk];
    for (int s = 0; s < sg; s++) run += part[bk][s];
#pragma unroll 8
    for (int i = 0; i < 64; i++) {
      const int th = sg * 64 + i;
      pfx[bk][th] = (unsigned short)run;
      run += cnt[bk][th];
    }
  }
  __syncthreads();
  int* st = sort_t + (size_t)bh * SS;
  int* ip = ipos + (size_t)bh * SS;
#pragma unroll
  for (int i = 0; i < 16; i++) {
    const int t = tid * 16 + i;
    const int bk = lb[t];
    const int pos = pfx[bk][tid]++;
    st[pos] = t;
    ip[t] = pos;
  }
}

// ---------------------------------------------------------------------------
// Kernel 3: chunked attention, bf16 inputs, transpose-free PV (R7, unchanged).
// ---------------------------------------------------------------------------
__global__ __launch_bounds__(256) void k_attn2(
    const unsigned short* __restrict__ qb, const unsigned short* __restrict__ kbg,
    const unsigned short* __restrict__ vbg, const int* __restrict__ sort_t,
    unsigned short* __restrict__ so, float* __restrict__ lse_u) {
  const int blk = blockIdx.x;
  const int b = blk >> 9;
  const int c = blk & 511;
  const int h = c >> 6, cc = c & 63;
  const int cp = (c + 511) & 511;
  const int hp = cp >> 6, ccp = cp & 63;

  __shared__ struct __align__(16) {
    unsigned short kb[128][72];
    unsigned short vs[128][68];
    union {
      unsigned short q[64][72];
      unsigned short p[64][136];
    } qp;
    int tk[128];
  } sm;

  const int tid = threadIdx.x;
  const int w = tid >> 6;
  const int lane = tid & 63;
  const int quad = lane >> 4;
  const int l16 = lane & 15;

  if (tid < 128) {
    const size_t srci = (tid < 64)
        ? (((size_t)b * HH + h) * SS + cc * 64 + tid)
        : (((size_t)b * HH + hp) * SS + ccp * 64 + (tid - 64));
    sm.tk[tid] = sort_t[srci];
  }
  __syncthreads();

  {
    const int j = tid >> 1, hf = tid & 1;
    const int trow = sm.tk[j];
    const s16x8* ksrc = (const s16x8*)(kbg + ((size_t)b * SS + trow) * DD + hf * 32);
    const s16x8* vsrc = (const s16x8*)(vbg + ((size_t)b * SS + trow) * DD + hf * 32);
    s16x8 kr[4], vr[4];
#pragma unroll
    for (int g = 0; g < 4; g++) { kr[g] = ksrc[g]; vr[g] = vsrc[g]; }
#pragma unroll
    for (int g = 0; g < 4; g++)
      *(s16x8*)&sm.kb[j][hf * 32 + g * 8] = kr[g];
#pragma unroll
    for (int g = 0; g < 4; g++) {
      *(s16x4*)&sm.vs[j][hf * 32 + g * 8] = (s16x4){vr[g][0], vr[g][1], vr[g][2], vr[g][3]};
      *(s16x4*)&sm.vs[j][hf * 32 + g * 8 + 4] = (s16x4){vr[g][4], vr[g][5], vr[g][6], vr[g][7]};
    }
    const int qi = tid >> 2, qq = tid & 3;
    const s16x8* qsrc = (const s16x8*)(qb + ((size_t)b * SS + sm.tk[qi]) * DD + qq * 16);
    const s16x8 q0 = qsrc[0], q1 = qsrc[1];
    *(s16x8*)&sm.qp.q[qi][qq * 16] = q0;
    *(s16x8*)&sm.qp.q[qi][qq * 16 + 8] = q1;
  }
  __syncthreads();

  f32x4 acc[8];
#pragma unroll
  for (int nt = 0; nt < 8; nt++) acc[nt] = (f32x4){0.f, 0.f, 0.f, 0.f};
  {
    const s16x8 a0 = *(const s16x8*)&sm.qp.q[w * 16 + l16][quad * 8];
    const s16x8 a1 = *(const s16x8*)&sm.qp.q[w * 16 + l16][32 + quad * 8];
#pragma unroll
    for (int nt = 0; nt < 8; nt++) {
      const s16x8 b0 = *(const s16x8*)&sm.kb[nt * 16 + l16][quad * 8];
      const s16x8 b1 = *(const s16x8*)&sm.kb[nt * 16 + l16][32 + quad * 8];
      acc[nt] = __builtin_amdgcn_mfma_f32_16x16x32_bf16(a0, b0, acc[nt], 0, 0, 0);
      acc[nt] = __builtin_amdgcn_mfma_f32_16x16x32_bf16(a1, b1, acc[nt], 0, 0, 0);
    }
  }

  int tqr[4];
#pragma unroll
  for (int r = 0; r < 4; r++) tqr[r] = sm.tk[w * 16 + quad * 4 + r];
  int tkc[8];
#pragma unroll
  for (int nt = 0; nt < 8; nt++) tkc[nt] = sm.tk[nt * 16 + l16];

#pragma unroll
  for (int nt = 0; nt < 8; nt++)
#pragma unroll
    for (int r = 0; r < 4; r++)
      if (tqr[r] == tkc[nt]) acc[nt][r] = -50000.0f;

  float rmax[4], lse[4], inv[4];
#pragma unroll
  for (int r = 0; r < 4; r++) {
    float m = acc[0][r];
#pragma unroll
    for (int nt = 1; nt < 8; nt++) m = fmaxf(m, acc[nt][r]);
    m = fmaxf(m, __shfl_xor(m, 1));
    m = fmaxf(m, __shfl_xor(m, 2));
    m = fmaxf(m, __shfl_xor(m, 4));
    m = fmaxf(m, __shfl_xor(m, 8));
    rmax[r] = m;
  }
#pragma unroll
  for (int r = 0; r < 4; r++) {
    float s = 0.f;
#pragma unroll
    for (int nt = 0; nt < 8; nt++) {
      const float e = __expf(acc[nt][r] - rmax[r]);
      acc[nt][r] = e;
      s += e;
    }
    s += __shfl_xor(s, 1);
    s += __shfl_xor(s, 2);
    s += __shfl_xor(s, 4);
    s += __shfl_xor(s, 8);
    inv[r] = 1.0f / s;
    lse[r] = __logf(s) + rmax[r];
  }

  if (l16 == 0) {
#pragma unroll
    for (int r = 0; r < 4; r++)
      lse_u[((size_t)b * SS + tqr[r]) * HH + h] = lse[r];
  }

  __syncthreads();

#pragma unroll
  for (int nt = 0; nt < 8; nt++)
#pragma unroll
    for (int r = 0; r < 4; r++)
      sm.qp.p[w * 16 + quad * 4 + r][nt * 16 + l16] = f2bf(acc[nt][r] * inv[r]);
  __syncthreads();

  f32x4 o[4];
#pragma unroll
  for (int nt = 0; nt < 4; nt++) o[nt] = (f32x4){0.f, 0.f, 0.f, 0.f};
#pragma unroll
  for (int kc = 0; kc < 4; kc++) {
    s16x8 av;
#pragma unroll
    for (int e = 0; e < 8; e++)
      av[e] = (short)sm.vs[kc * 32 + quad * 8 + e][w * 16 + l16];
#pragma unroll
    for (int nt = 0; nt < 4; nt++) {
      const s16x8 bp = *(const s16x8*)&sm.qp.p[nt * 16 + l16][kc * 32 + quad * 8];
      o[nt] = __builtin_amdgcn_mfma_f32_16x16x32_bf16(av, bp, o[nt], 0, 0, 0);
    }
  }

#pragma unroll
  for (int nt = 0; nt < 4; nt++) {
    const int t = sm.tk[nt * 16 + l16];
    s16x4 ov;
#pragma unroll
    for (int r = 0; r < 4; r++) ov[r] = (short)f2bf(o[nt][r]);
    unsigned short* dst =
        so + (((size_t)b * SS + t) * HH + h) * DD + w * 16 + quad * 4;
    *(s16x4*)dst = ov;
  }
}

// ---------------------------------------------------------------------------
// Kernel 4: streaming combine over hashes (R7, unchanged).
// ---------------------------------------------------------------------------
__global__ __launch_bounds__(256) void k_combine2(
    const unsigned short* __restrict__ so, const float* __restrict__ lse_u,
    float* __restrict__ out) {
  const size_t idx = (size_t)blockIdx.x * 256 + threadIdx.x;
  const int f = (int)(idx & 63);
  const size_t bt = idx >> 6;

  float l[HH];
#pragma unroll
  for (int h = 0; h < HH; h++) l[h] = lse_u[bt * HH + h];
  float m = l[0];
#pragma unroll
  for (int h = 1; h < HH; h++) m = fmaxf(m, l[h]);
  float den = 0.f, num = 0.f;
#pragma unroll
  for (int h = 0; h < HH; h++) {
    const float wgt = __expf(l[h] - m);
    den += wgt;
    num += wgt * bf2f(so[(bt * HH + h) * DD + f]);
  }
  out[idx] = num / den;
}

// ---------------------------------------------------------------------------
// Fallback-path hash (R8's fp32 k_hash_f32) + atomic attention (R1-proven).
// ---------------------------------------------------------------------------
__global__ __launch_bounds__(256, 2) void k_hash_f32(
    const float* __restrict__ qk, const float* __restrict__ rot,
    int* __restrict__ bucket_local, float* __restrict__ buckets_out,
    int* __restrict__ needy_list, int* __restrict__ needy_count) {
  __shared__ float lb[128 * 65];
  const int b = blockIdx.x;
  const int t0 = blockIdx.y * 128;
  const int tid = threadIdx.x;

  {
    const int row = tid >> 1, hf = (tid & 1) * 32;
    const float4* src =
        (const float4*)(qk + ((size_t)b * SS + t0 + row) * DD + hf);
    float* dst = &lb[row * 65 + hf];
#pragma unroll
    for (int g = 0; g < 8; g++) {
      const float4 vv = src[g];
      dst[g * 4 + 0] = vv.x; dst[g * 4 + 1] = vv.y;
      dst[g * 4 + 2] = vv.z; dst[g * 4 + 3] = vv.w;
    }
  }
  __syncthreads();

  const int w = tid >> 6;
  const int l = tid & 63;
  const int hb = __builtin_amdgcn_readfirstlane(w);

  for (int hp = 0; hp < 2; hp++) {
    const int h = hb + hp * 4;
    const float* rbase = rot + ((size_t)b * DD * HH + h) * NBH;
    const size_t rstride = HH * NBH;

    float acc0[NBH], acc1[NBH];
#pragma unroll
    for (int i = 0; i < NBH; i++) { acc0[i] = 0.f; acc1[i] = 0.f; }

    float4 bufA[8], bufB[8];
#pragma unroll
    for (int i4 = 0; i4 < 8; i4++) bufA[i4] = ((const float4*)rbase)[i4];

    for (int f = 0; f < DD; f += 2) {
      {
        const float4* r4 = (const float4*)(rbase + (size_t)(f + 1) * rstride);
#pragma unroll
        for (int i4 = 0; i4 < 8; i4++) bufB[i4] = r4[i4];
      }
      {
        const float q0 = lb[l * 65 + f];
        const float q1 = lb[(l + 64) * 65 + f];
#pragma unroll
        for (int i4 = 0; i4 < 8; i4++) {
          const float4 rv = bufA[i4];
          acc0[i4*4+0] = fmaf(q0, rv.x, acc0[i4*4+0]);
          acc0[i4*4+1] = fmaf(q0, rv.y, acc0[i4*4+1]);
          acc0[i4*4+2] = fmaf(q0, rv.z, acc0[i4*4+2]);
          acc0[i4*4+3] = fmaf(q0, rv.w, acc0[i4*4+3]);
          acc1[i4*4+0] = fmaf(q1, rv.x, acc1[i4*4+0]);
          acc1[i4*4+1] = fmaf(q1, rv.y, acc1[i4*4+1]);
          acc1[i4*4+2] = fmaf(q1, rv.z, acc1[i4*4+2]);
          acc1[i4*4+3] = fmaf(q1, rv.w, acc1[i4*4+3]);
        }
      }
      if (f + 2 < DD) {
        const float4* r4 = (const float4*)(rbase + (size_t)(f + 2) * rstride);
#pragma unroll
        for (int i4 = 0; i4 < 8; i4++) bufA[i4] = r4[i4];
      }
      {
        const float q0 = lb[l * 65 + f + 1];
        const float q1 = lb[(l + 64) * 65 + f + 1];
#pragma unroll
        for (int i4 = 0; i4 < 8; i4++) {
          const float4 rv = bufB[i4];
          acc0[i4*4+0] = fmaf(q0, rv.x, acc0[i4*4+0]);
          acc0[i4*4+1] = fmaf(q0, rv.y, acc0[i4*4+1]);
          acc0[i4*4+2] = fmaf(q0, rv.z, acc0[i4*4+2]);
          acc0[i4*4+3] = fmaf(q0, rv.w, acc0[i4*4+3]);
          acc1[i4*4+0] = fmaf(q1, rv.x, acc1[i4*4+0]);
          acc1[i4*4+1] = fmaf(q1, rv.y, acc1[i4*4+1]);
          acc1[i4*4+2] = fmaf(q1, rv.z, acc1[i4*4+2]);
          acc1[i4*4+3] = fmaf(q1, rv.w, acc1[i4*4+3]);
        }
      }
    }

#pragma unroll
    for (int tok = 0; tok < 2; tok++) {
      const float* acc = tok ? acc1 : acc0;
      float best = -3.0e38f, second = -3.0e38f;
      int bi = 0;
#pragma unroll
      for (int i = 0; i < 64; i++) {
        const float vv = (i < NBH) ? acc[i] : -acc[i - NBH];
        if (vv > best) { second = best; best = vv; bi = i; }
        else if (vv > second) { second = vv; }
      }
      const int t = t0 + tok * 64 + l;
      bucket_local[((size_t)b * HH + h) * SS + t] = bi;
      buckets_out[(size_t)b * (HH * SS) + (size_t)h * SS + t] =
          (float)(h * NB + bi);
      if (best - second <= MARGIN) {
        const int slot = atomicAdd(needy_count, 1);
        needy_list[slot] = (((b << 3) | h) << 12) | t;
      }
    }
  }
}

__global__ __launch_bounds__(256) void k_attn_atomic(
    const float* __restrict__ qk, const float* __restrict__ v,
    const int* __restrict__ sort_t, float* __restrict__ num,
    float* __restrict__ den) {
  const int blk = blockIdx.x;
  const int b = blk >> 9;
  const int c = blk & 511;
  const int h = c >> 6, cc = c & 63;
  const int cp = (c + 511) & 511;
  const int hp = cp >> 6, ccp = cp & 63;

  __shared__ union {
    struct {
      float qt[DD * 64];
      float kt[DD * 128];
      int   tq[64];
      int   tk[128];
      float nrm[128];
      float red[16 * 64];
      float rmax[64];
      float rsum[64];
    } a;
    struct {
      float pt[128 * 64];
      float vs[128 * 64];
    } p;
  } sm;

  const int tid = threadIdx.x;

  if (tid < 64)
    sm.a.tq[tid] = sort_t[((size_t)b * HH + h) * SS + cc * 64 + tid];
  if (tid >= 128) {
    const int j = tid - 128;
    const size_t src = (j < 64) ? (((size_t)b * HH + h) * SS + cc * 64 + j)
                                : (((size_t)b * HH + hp) * SS + ccp * 64 + (j - 64));
    sm.a.tk[j] = sort_t[src];
  }
  if (tid >= 64 && tid < 192) sm.a.nrm[tid - 64] = 0.f;
  __syncthreads();

  {
    const int qi = tid >> 2, qq = tid & 3;
    const float4* qsrc =
        (const float4*)(qk + ((size_t)b * SS + sm.a.tq[qi]) * DD) + qq * 4;
#pragma unroll
    for (int k4 = 0; k4 < 4; k4++) {
      float4 val = qsrc[k4];
      const int f = qq * 16 + k4 * 4;
      sm.a.qt[(f + 0) * 64 + qi] = val.x;
      sm.a.qt[(f + 1) * 64 + qi] = val.y;
      sm.a.qt[(f + 2) * 64 + qi] = val.z;
      sm.a.qt[(f + 3) * 64 + qi] = val.w;
    }
    const int j = tid >> 1, hhf = tid & 1;
    const float4* ksrc =
        (const float4*)(qk + ((size_t)b * SS + sm.a.tk[j]) * DD) + hhf * 8;
    float ss = 0.f;
#pragma unroll
    for (int k4 = 0; k4 < 8; k4++) {
      float4 val = ksrc[k4];
      const int f = hhf * 32 + k4 * 4;
      sm.a.kt[(f + 0) * 128 + j] = val.x;
      sm.a.kt[(f + 1) * 128 + j] = val.y;
      sm.a.kt[(f + 2) * 128 + j] = val.z;
      sm.a.kt[(f + 3) * 128 + j] = val.w;
      ss += val.x * val.x + val.y * val.y + val.z * val.z + val.w * val.w;
    }
    atomicAdd(&sm.a.nrm[j], ss);
  }
  __syncthreads();
  if (tid < 128) {
    const float n = sqrtf(sm.a.nrm[tid]) + 1e-6f;
    sm.a.nrm[tid] = 0.125f / n;
  }
  float4 vreg[8];
  {
    const int j = tid >> 1, hhf = tid & 1;
    const float4* vsrc =
        (const float4*)(v + ((size_t)b * SS + sm.a.tk[j]) * DD) + hhf * 8;
#pragma unroll
    for (int k4 = 0; k4 < 8; k4++) vreg[k4] = vsrc[k4];
  }
  __syncthreads();

  const int qi0 = (tid & 15) * 4;
  const int j0g = (tid >> 4) * 8;
  const int kg = tid >> 4;
  float acc[4][8];
#pragma unroll
  for (int i = 0; i < 4; i++)
#pragma unroll
    for (int j = 0; j < 8; j++) acc[i][j] = 0.f;

#pragma unroll 8
  for (int f = 0; f < DD; f++) {
    float4 qv = *(const float4*)&sm.a.qt[f * 64 + qi0];
    float4 k0 = *(const float4*)&sm.a.kt[f * 128 + j0g];
    float4 k1 = *(const float4*)&sm.a.kt[f * 128 + j0g + 4];
    float qa[4] = {qv.x, qv.y, qv.z, qv.w};
    float ka[8] = {k0.x, k0.y, k0.z, k0.w, k1.x, k1.y, k1.z, k1.w};
#pragma unroll
    for (int i = 0; i < 4; i++)
#pragma unroll
      for (int j = 0; j < 8; j++) acc[i][j] = fmaf(qa[i], ka[j], acc[i][j]);
  }

  int tqr[4];
#pragma unroll
  for (int i = 0; i < 4; i++) tqr[i] = sm.a.tq[qi0 + i];
  int tkr[8]; float scl[8];
#pragma unroll
  for (int j = 0; j < 8; j++) {
    tkr[j] = sm.a.tk[j0g + j];
    scl[j] = sm.a.nrm[j0g + j];
  }
#pragma unroll
  for (int i = 0; i < 4; i++)
#pragma unroll
    for (int j = 0; j < 8; j++) {
      const float dv = acc[i][j] * scl[j];
      acc[i][j] = (tqr[i] == tkr[j]) ? -50000.0f : dv;
    }

  float pmax[4];
#pragma unroll
  for (int i = 0; i < 4; i++) {
    float m = acc[i][0];
#pragma unroll
    for (int j = 1; j < 8; j++) m = fmaxf(m, acc[i][j]);
    pmax[i] = m;
  }
#pragma unroll
  for (int i = 0; i < 4; i++) sm.a.red[kg * 64 + qi0 + i] = pmax[i];
  __syncthreads();
  if (tid < 64) {
    float m = -3.0e38f;
#pragma unroll
    for (int g = 0; g < 16; g++) m = fmaxf(m, sm.a.red[g * 64 + tid]);
    sm.a.rmax[tid] = m;
  }
  __syncthreads();
  float psum[4];
#pragma unroll
  for (int i = 0; i < 4; i++) {
    const float rm = sm.a.rmax[qi0 + i];
    float s = 0.f;
#pragma unroll
    for (int j = 0; j < 8; j++) {
      const float e = __expf(acc[i][j] - rm);
      acc[i][j] = e;
      s += e;
    }
    psum[i] = s;
  }
#pragma unroll
  for (int i = 0; i < 4; i++) sm.a.red[kg * 64 + qi0 + i] = psum[i];
  __syncthreads();
  if (tid < 64) {
    float s = 0.f;
#pragma unroll
    for (int g = 0; g < 16; g++) s += sm.a.red[g * 64 + tid];
    sm.a.rsum[tid] = s;
  }
  __syncthreads();
  float lse[4], isum[4];
#pragma unroll
  for (int i = 0; i < 4; i++) {
    const float rm = sm.a.rmax[qi0 + i];
    const float s = sm.a.rsum[qi0 + i];
    isum[i] = 1.0f / s;
    lse[i] = __logf(s) + rm;
  }
  __syncthreads();

#pragma unroll
  for (int j = 0; j < 8; j++)
#pragma unroll
    for (int i = 0; i < 4; i++)
      sm.p.pt[(j0g + j) * 64 + qi0 + i] = acc[i][j] * isum[i];
  {
    const int j = tid >> 1, hhf = tid & 1;
#pragma unroll
    for (int k4 = 0; k4 < 8; k4++)
      *(float4*)&sm.p.vs[j * 64 + hhf * 32 + k4 * 4] = vreg[k4];
  }
  __syncthreads();

  const int f0 = (tid >> 4) * 4;
  float o[4][4];
#pragma unroll
  for (int i = 0; i < 4; i++)
#pragma unroll
    for (int j = 0; j < 4; j++) o[i][j] = 0.f;

#pragma unroll 8
  for (int j = 0; j < 128; j++) {
    float4 pv = *(const float4*)&sm.p.pt[j * 64 + qi0];
    float4 vv = *(const float4*)&sm.p.vs[j * 64 + f0];
    float pa[4] = {pv.x, pv.y, pv.z, pv.w};
    float va[4] = {vv.x, vv.y, vv.z, vv.w};
#pragma unroll
    for (int i = 0; i < 4; i++)
#pragma unroll
      for (int j2 = 0; j2 < 4; j2++) o[i][j2] = fmaf(pa[i], va[j2], o[i][j2]);
  }

#pragma unroll
  for (int i = 0; i < 4; i++) {
    const float w = __expf(lse[i]);
    float* dst = num + ((size_t)b * SS + tqr[i]) * DD + f0;
#pragma unroll
    for (int j = 0; j < 4; j++) atomicAdd(dst + j, o[i][j] * w);
    if (kg == 0) atomicAdd(den + (size_t)b * SS + tqr[i], w);
  }
}

__global__ __launch_bounds__(256) void k_final(float* __restrict__ o,
                                               const float* __restrict__ den) {
  const size_t i = (size_t)blockIdx.x * 256 + threadIdx.x;
  o[i] = o[i] / den[i >> 6];
}

extern "C" void kernel_launch(void* const* d_in, const int* in_sizes, int n_in,
                              void* d_out, int out_size, void* d_ws,
                              size_t ws_size, hipStream_t stream) {
  const float* qk  = (const float*)d_in[0];
  const float* v   = (const float*)d_in[1];
  const float* rot = (const float*)d_in[2];

  float* out_attn = (float*)d_out;                      // B*S*D floats
  float* buckets_out = out_attn + (size_t)BB * SS * DD; // B*H*S floats

  const size_t BHS = (size_t)BB * HH * SS;              // 524288
  const size_t BSD = (size_t)BB * SS * DD;              // 4194304
  const size_t RT  = (size_t)BB * HH * 32 * DD;         // 262144
  int* bucket_local = (int*)d_ws;
  int* sort_t = bucket_local + BHS;                     // doubles as needy_list
  int* ipos = sort_t + BHS;                             // ipos[0] = needy_count
  float* lse_u = (float*)(ipos + BHS);                  // [b][t][h]
  unsigned short* qb16 = (unsigned short*)(lse_u + BHS);
  unsigned short* kb16 = qb16 + BSD;
  unsigned short* vb16 = kb16 + BSD;
  unsigned short* so_u = vb16 + BSD;                    // [b][t][h][f] bf16
  unsigned short* rTh = so_u + BHS * DD;
  unsigned short* rTl = rTh + RT;

  const size_t NEED2 =
      4 * BHS * 4 + 3 * BSD * 2 + BHS * DD * 2 + 2 * RT * 2;  // ~101.7 MB

  if (ws_size >= NEED2) {
    hipMemsetAsync(ipos, 0, sizeof(int), stream);       // needy_count = 0
    k_conv<<<2 * BB * SS * 4 / 256, 256, 0, stream>>>(qk, v, qb16, kb16, vb16);
    k_rotT<<<BB, 256, 0, stream>>>(rot, rTh, rTl);
    k_hash_mfma<<<dim3(BB, SS / 128), 256, 0, stream>>>(
        qk, rTh, rTl, bucket_local, buckets_out, sort_t, ipos);
    k_hash_fix<<<256, 256, 0, stream>>>(qk, rot, sort_t, ipos, bucket_local,
                                        buckets_out);
    k_sort<<<BB * HH, 256, 0, stream>>>(bucket_local, sort_t, ipos);
    k_attn2<<<BB * NCH, 256, 0, stream>>>(qb16, kb16, vb16, sort_t, so_u, lse_u);
    k_combine2<<<(BB * SS * DD) / 256, 256, 0, stream>>>(so_u, lse_u, out_attn);
  } else {
    float* den = (float*)(sort_t + 2 * BHS);
    hipMemsetAsync(out_attn, 0, (size_t)BB * SS * DD * sizeof(float), stream);
    hipMemsetAsync(den, 0, (size_t)BB * SS * sizeof(float), stream);
    hipMemsetAsync(ipos, 0, sizeof(int), stream);
    k_hash_f32<<<dim3(BB, SS / 128), 256, 0, stream>>>(
        qk, rot, bucket_local, buckets_out, sort_t, ipos);
    k_hash_fix<<<256, 256, 0, stream>>>(qk, rot, sort_t, ipos, bucket_local,
                                        buckets_out);
    k_sort<<<BB * HH, 256, 0, stream>>>(bucket_local, sort_t, ipos);
    k_attn_atomic<<<BB * NCH, 256, 0, stream>>>(qk, v, sort_t, out_attn, den);
    k_final<<<(BB * SS * DD) / 256, 256, 0, stream>>>(out_attn, den);
  }
}

// Round 10
// 237.706 us; speedup vs baseline: 1.0309x; 1.0309x over previous
//
#include <hip/hip_runtime.h>
#include <math.h>

#define BB   16
#define SS   4096
#define DD   64
#define HH   8
#define NBH  32
#define NB   64
#define NCH  512     // global chunks per batch = HH * 64

typedef __attribute__((ext_vector_type(8))) short s16x8;   // 8 bf16
typedef __attribute__((ext_vector_type(4))) short s16x4;   // 4 bf16
typedef __attribute__((ext_vector_type(4))) float f32x4;

static __device__ __forceinline__ unsigned short f2bf(float x) {
  union { float f; unsigned u; } a; a.f = x;
  unsigned r = a.u + 0x7fffu + ((a.u >> 16) & 1u);   // RNE
  return (unsigned short)(r >> 16);
}
static __device__ __forceinline__ float bf2f(unsigned short u) {
  union { unsigned u; float f; } a; a.u = ((unsigned)u) << 16;
  return a.f;
}

// ---------------------------------------------------------------------------
// Kernel 0: streaming fp32->bf16 conversion (R7, unchanged).
// ---------------------------------------------------------------------------
__global__ __launch_bounds__(256) void k_conv(
    const float* __restrict__ qk, const float* __restrict__ v,
    unsigned short* __restrict__ qb, unsigned short* __restrict__ kb,
    unsigned short* __restrict__ vb) {
  const int gid = blockIdx.x * 256 + threadIdx.x;
  const int half = BB * SS * 4;
  const bool isV = gid >= half;
  const int id = isV ? gid - half : gid;
  const int row = id >> 2, q4 = id & 3;

  const float4* src =
      (const float4*)((isV ? v : qk) + (size_t)row * DD + q4 * 16);
  float vals[16];
#pragma unroll
  for (int g = 0; g < 4; g++) {
    const float4 a = src[g];
    vals[g * 4 + 0] = a.x; vals[g * 4 + 1] = a.y;
    vals[g * 4 + 2] = a.z; vals[g * 4 + 3] = a.w;
  }

  if (!isV) {
    float ss = 0.f;
#pragma unroll
    for (int i = 0; i < 16; i++) ss += vals[i] * vals[i];
    ss += __shfl_xor(ss, 1);
    ss += __shfl_xor(ss, 2);
    const float scl = 0.125f / (sqrtf(ss) + 1e-6f);
    unsigned short qo[16], ko[16];
#pragma unroll
    for (int i = 0; i < 16; i++) {
      qo[i] = f2bf(vals[i]);
      ko[i] = f2bf(vals[i] * scl);
    }
    unsigned short* qd = qb + (size_t)row * DD + q4 * 16;
    unsigned short* kd = kb + (size_t)row * DD + q4 * 16;
    *(s16x8*)qd = *(const s16x8*)&qo[0];
    *(s16x8*)(qd + 8) = *(const s16x8*)&qo[8];
    *(s16x8*)kd = *(const s16x8*)&ko[0];
    *(s16x8*)(kd + 8) = *(const s16x8*)&ko[8];
  } else {
    unsigned short vo[16];
#pragma unroll
    for (int i = 0; i < 16; i++) vo[i] = f2bf(vals[i]);
    unsigned short* vd = vb + (size_t)row * DD + q4 * 16;
    *(s16x8*)vd = *(const s16x8*)&vo[0];
    *(s16x8*)(vd + 8) = *(const s16x8*)&vo[8];
  }
}

// ---------------------------------------------------------------------------
// Kernel 0b: transpose rotations to rT[b][h][i][f], split hi/lo bf16.
// Also zeroes needy_count (replaces a memset dispatch).
// ---------------------------------------------------------------------------
__global__ __launch_bounds__(256) void k_rotT(
    const float* __restrict__ rot, unsigned short* __restrict__ rTh,
    unsigned short* __restrict__ rTl, int* __restrict__ needy_count) {
  __shared__ float slab[32][256];
  const int b = blockIdx.x;
  const int tid = threadIdx.x;
  if (b == 0 && tid == 0) *needy_count = 0;

  for (int st = 0; st < 2; st++) {
#pragma unroll
    for (int fr = 0; fr < 32; fr++)
      slab[fr][tid] = rot[(size_t)b * (DD * HH * NBH) +
                          (size_t)(st * 32 + fr) * 256 + tid];
    __syncthreads();
    unsigned short hi[32], lo[32];
#pragma unroll
    for (int fr = 0; fr < 32; fr++) {
      const float x = slab[fr][tid];
      const unsigned short hh = f2bf(x);
      hi[fr] = hh;
      lo[fr] = f2bf(x - bf2f(hh));
    }
    unsigned short* dh = rTh + ((size_t)b * 256 + tid) * DD + st * 32;
    unsigned short* dl = rTl + ((size_t)b * 256 + tid) * DD + st * 32;
#pragma unroll
    for (int g = 0; g < 4; g++) {
      *(s16x8*)(dh + g * 8) = *(const s16x8*)&hi[g * 8];
      *(s16x8*)(dl + g * 8) = *(const s16x8*)&lo[g * 8];
    }
    __syncthreads();
  }
}

// ---------------------------------------------------------------------------
// Kernel 1a: MFMA LSH hash. R9's version ran ~80us: the static-trip h-loop
// was unrollable -> 8 live B-frag sets -> VGPR spill (same disease as R8's
// acc spill). Fix: #pragma unroll 1 on the h-loop + B-frags scoped per-nt
// (16 live VGPRs). Math order per (token,bucket) UNCHANGED -> bit-identical
// buckets/needy set (absmax 10.0 vs np is one fixed near-tie; do not
// perturb MARGIN/logic).
// ---------------------------------------------------------------------------
#define MARGIN 1e-2f

__global__ __launch_bounds__(256, 2) void k_hash_mfma(
    const float* __restrict__ qk, const unsigned short* __restrict__ rTh,
    const unsigned short* __restrict__ rTl, int* __restrict__ bucket_local,
    float* __restrict__ buckets_out, int* __restrict__ needy_list,
    int* __restrict__ needy_count) {
  __shared__ struct __align__(16) {
    unsigned short ah[128][72];   // 18432 B
    unsigned short al[128][72];   // 18432 B
    float sc[128][33];            // 16896 B
  } sm;
  const int b = blockIdx.x;
  const int t0 = blockIdx.y * 128;
  const int tid = threadIdx.x;
  const int w = tid >> 6, lane = tid & 63;
  const int quad = lane >> 4, l16 = lane & 15;

  // ---- stage A hi/lo (thread = half a token row, 8-elem groups) ----
  {
    const int row = tid >> 1, hf = tid & 1;
    const float4* src =
        (const float4*)(qk + ((size_t)b * SS + t0 + row) * DD + hf * 32);
#pragma unroll
    for (int gg = 0; gg < 4; gg++) {
      const float4 v0 = src[gg * 2], v1 = src[gg * 2 + 1];
      const float a[8] = {v0.x, v0.y, v0.z, v0.w, v1.x, v1.y, v1.z, v1.w};
      unsigned short hi[8], lo[8];
#pragma unroll
      for (int e = 0; e < 8; e++) {
        const unsigned short hh = f2bf(a[e]);
        hi[e] = hh;
        lo[e] = f2bf(a[e] - bf2f(hh));
      }
      *(s16x8*)&sm.ah[row][hf * 32 + gg * 8] = *(const s16x8*)hi;
      *(s16x8*)&sm.al[row][hf * 32 + gg * 8] = *(const s16x8*)lo;
    }
  }
  __syncthreads();

  // ---- hoist A-frags (independent of h) ----
  s16x8 Ah[2][2], Al[2][2];
#pragma unroll
  for (int mtl = 0; mtl < 2; mtl++) {
    const int row = (w * 2 + mtl) * 16 + l16;
#pragma unroll
    for (int ks = 0; ks < 2; ks++) {
      Ah[mtl][ks] = *(const s16x8*)&sm.ah[row][ks * 32 + quad * 8];
      Al[mtl][ks] = *(const s16x8*)&sm.al[row][ks * 32 + quad * 8];
    }
  }

#pragma unroll 1
  for (int h = 0; h < HH; h++) {
#pragma unroll
    for (int nt = 0; nt < 2; nt++) {
      const size_t rrow = (((size_t)b * HH + h) * 32 + nt * 16 + l16) * DD;
      s16x8 Bh2[2], Bl2[2];
#pragma unroll
      for (int ks = 0; ks < 2; ks++) {
        Bh2[ks] = *(const s16x8*)&rTh[rrow + ks * 32 + quad * 8];
        Bl2[ks] = *(const s16x8*)&rTl[rrow + ks * 32 + quad * 8];
      }
#pragma unroll
      for (int mtl = 0; mtl < 2; mtl++) {
        f32x4 acc = (f32x4){0.f, 0.f, 0.f, 0.f};
#pragma unroll
        for (int ks = 0; ks < 2; ks++) {
          acc = __builtin_amdgcn_mfma_f32_16x16x32_bf16(Al[mtl][ks], Bl2[ks], acc, 0, 0, 0);
          acc = __builtin_amdgcn_mfma_f32_16x16x32_bf16(Al[mtl][ks], Bh2[ks], acc, 0, 0, 0);
          acc = __builtin_amdgcn_mfma_f32_16x16x32_bf16(Ah[mtl][ks], Bl2[ks], acc, 0, 0, 0);
          acc = __builtin_amdgcn_mfma_f32_16x16x32_bf16(Ah[mtl][ks], Bh2[ks], acc, 0, 0, 0);
        }
#pragma unroll
        for (int r = 0; r < 4; r++)
          sm.sc[(w * 2 + mtl) * 16 + quad * 4 + r][nt * 16 + l16] = acc[r];
      }
    }
    __syncthreads();

    if (lane < 32) {
      const int tloc = w * 32 + lane;
      float best = -3.0e38f, second = -3.0e38f;
      int bi = 0;
#pragma unroll 8
      for (int i = 0; i < 32; i++) {
        const float vv = sm.sc[tloc][i];
        if (vv > best) { second = best; best = vv; bi = i; }
        else if (vv > second) second = vv;
      }
#pragma unroll 8
      for (int i = 32; i < 64; i++) {
        const float vv = -sm.sc[tloc][i - 32];
        if (vv > best) { second = best; best = vv; bi = i; }
        else if (vv > second) second = vv;
      }
      const int t = t0 + tloc;
      bucket_local[((size_t)b * HH + h) * SS + t] = bi;
      buckets_out[(size_t)b * (HH * SS) + (size_t)h * SS + t] =
          (float)(h * NB + bi);
      if (best - second <= MARGIN) {
        const int slot = atomicAdd(needy_count, 1);
        needy_list[slot] = (((b << 3) | h) << 12) | t;
      }
    }
    __syncthreads();
  }
}

// ---------------------------------------------------------------------------
// Kernel 1b: exact fp64 recompute for near-ties (R6, unchanged).
// ---------------------------------------------------------------------------
__global__ __launch_bounds__(256) void k_hash_fix(
    const float* __restrict__ qk, const float* __restrict__ rot,
    const int* __restrict__ needy_list, const int* __restrict__ needy_count,
    int* __restrict__ bucket_local, float* __restrict__ buckets_out) {
  const int n = *needy_count;
  const int hw = (blockIdx.x * 256 + (int)threadIdx.x) >> 5;
  const int li = threadIdx.x & 31;
  const int nhw = gridDim.x * 8;

  for (int idx = hw; idx < n; idx += nhw) {
    const int code = needy_list[idx];
    const int t = code & 4095;
    const int bh = code >> 12;
    const int b = bh >> 3, h = bh & 7;

    const float* qrow = qk + ((size_t)b * SS + t) * DD;
    const float* rcol = rot + ((size_t)b * DD * HH + h) * NBH + li;

    double acc = 0.0;
#pragma unroll 8
    for (int f = 0; f < DD; f++)
      acc += (double)qrow[f] * (double)rcol[(size_t)f * (HH * NBH)];

    double bv = acc;
    int bi = li;
    if (-acc > bv) { bv = -acc; bi = li + 32; }
#pragma unroll
    for (int off = 1; off < 32; off <<= 1) {
      const double ov = __shfl_xor(bv, off);
      const int oi = __shfl_xor(bi, off);
      if (ov > bv || (ov == bv && oi < bi)) { bv = ov; bi = oi; }
    }
    if (li == 0) {
      bucket_local[((size_t)b * HH + h) * SS + t] = bi;
      buckets_out[(size_t)b * (HH * SS) + (size_t)h * SS + t] =
          (float)(h * NB + bi);
    }
  }
}

// ---------------------------------------------------------------------------
// Kernel 2: parallel stable counting-rank sort per (b,h) (R6, unchanged).
// ---------------------------------------------------------------------------
__global__ __launch_bounds__(256) void k_sort(
    const int* __restrict__ bucket_local, int* __restrict__ sort_t,
    int* __restrict__ ipos) {
  __shared__ unsigned short lb[SS];
  __shared__ unsigned char  cnt[NB][256];
  __shared__ unsigned short pfx[NB][256];
  __shared__ int part[NB][4];
  __shared__ int tot[NB];
  __shared__ int base[NB];

  const int bh = blockIdx.x;
  const int tid = threadIdx.x;
  const int* src = bucket_local + (size_t)bh * SS;

  int* czero = (int*)&cnt[0][0];
#pragma unroll
  for (int i = 0; i < 16; i++) czero[tid + i * 256] = 0;
  __syncthreads();

#pragma unroll
  for (int i = 0; i < 16; i++) {
    const int t = tid * 16 + i;
    const int v = src[t];
    lb[t] = (unsigned short)v;
    cnt[v][tid]++;
  }
  __syncthreads();

  {
    const int bk = tid & 63, sg = tid >> 6;
    int s = 0;
#pragma unroll 8
    for (int i = 0; i < 64; i++) s += cnt[bk][sg * 64 + i];
    part[bk][sg] = s;
  }
  __syncthreads();
  if (tid < NB) tot[tid] = part[tid][0] + part[tid][1] + part[tid][2] + part[tid][3];
  __syncthreads();
  if (tid == 0) {
    int r = 0;
    for (int i = 0; i < NB; i++) { base[i] = r; r += tot[i]; }
  }
  __syncthreads();
  {
    const int bk = tid & 63, sg = tid >> 6;
    int run = base[bk];
    for (int s = 0; s < sg; s++) run += part[bk][s];
#pragma unroll 8
    for (int i = 0; i < 64; i++) {
      const int th = sg * 64 + i;
      pfx[bk][th] = (unsigned short)run;
      run += cnt[bk][th];
    }
  }
  __syncthreads();
  int* st = sort_t + (size_t)bh * SS;
  int* ip = ipos + (size_t)bh * SS;
#pragma unroll
  for (int i = 0; i < 16; i++) {
    const int t = tid * 16 + i;
    const int bk = lb[t];
    const int pos = pfx[bk][tid]++;
    st[pos] = t;
    ip[t] = pos;
  }
}

// ---------------------------------------------------------------------------
// Kernel 3: chunked attention. R10: Q never staged in LDS (A-frags load
// 16B/lane from global qb — 4 lanes/row coalesced, L2-hit), and P overlays
// the dead K region (K dead after QK^T; existing barrier separates).
// LDS 53760 -> 36352 B => 4 blocks/CU (was 2). Numerics bit-identical.
// ---------------------------------------------------------------------------
__global__ __launch_bounds__(256, 4) void k_attn2(
    const unsigned short* __restrict__ qb, const unsigned short* __restrict__ kbg,
    const unsigned short* __restrict__ vbg, const int* __restrict__ sort_t,
    unsigned short* __restrict__ so, float* __restrict__ lse_u) {
  const int blk = blockIdx.x;
  const int b = blk >> 9;
  const int c = blk & 511;
  const int h = c >> 6, cc = c & 63;
  const int cp = (c + 511) & 511;
  const int hp = cp >> 6, ccp = cp & 63;

  __shared__ struct __align__(16) {
    union {
      unsigned short kb[128][72];   // K during QK^T (18432 B)
      unsigned short p[64][136];    // probs during PV (17408 B)
    } kp;
    unsigned short vs[128][68];     // 17408 B
    int tk[128];                    // 512 B -> total 36352
  } sm;

  const int tid = threadIdx.x;
  const int w = tid >> 6;
  const int lane = tid & 63;
  const int quad = lane >> 4;
  const int l16 = lane & 15;

  if (tid < 128) {
    const size_t srci = (tid < 64)
        ? (((size_t)b * HH + h) * SS + cc * 64 + tid)
        : (((size_t)b * HH + hp) * SS + ccp * 64 + (tid - 64));
    sm.tk[tid] = sort_t[srci];
  }
  __syncthreads();

  // ---- stage K, V (2 thr/row) ----
  {
    const int j = tid >> 1, hf = tid & 1;
    const int trow = sm.tk[j];
    const s16x8* ksrc = (const s16x8*)(kbg + ((size_t)b * SS + trow) * DD + hf * 32);
    const s16x8* vsrc = (const s16x8*)(vbg + ((size_t)b * SS + trow) * DD + hf * 32);
    s16x8 kr[4], vr[4];
#pragma unroll
    for (int g = 0; g < 4; g++) { kr[g] = ksrc[g]; vr[g] = vsrc[g]; }
#pragma unroll
    for (int g = 0; g < 4; g++)
      *(s16x8*)&sm.kp.kb[j][hf * 32 + g * 8] = kr[g];
#pragma unroll
    for (int g = 0; g < 4; g++) {
      *(s16x4*)&sm.vs[j][hf * 32 + g * 8] = (s16x4){vr[g][0], vr[g][1], vr[g][2], vr[g][3]};
      *(s16x4*)&sm.vs[j][hf * 32 + g * 8 + 4] = (s16x4){vr[g][4], vr[g][5], vr[g][6], vr[g][7]};
    }
  }
  // ---- Q A-frags direct from global (tk valid after first barrier) ----
  const int tq_frag = sm.tk[w * 16 + l16];
  const unsigned short* qrowp = qb + ((size_t)b * SS + tq_frag) * DD;
  const s16x8 a0 = *(const s16x8*)(qrowp + quad * 8);
  const s16x8 a1 = *(const s16x8*)(qrowp + 32 + quad * 8);
  __syncthreads();

  // ---- QK^T ----
  f32x4 acc[8];
#pragma unroll
  for (int nt = 0; nt < 8; nt++) acc[nt] = (f32x4){0.f, 0.f, 0.f, 0.f};
#pragma unroll
  for (int nt = 0; nt < 8; nt++) {
    const s16x8 b0 = *(const s16x8*)&sm.kp.kb[nt * 16 + l16][quad * 8];
    const s16x8 b1 = *(const s16x8*)&sm.kp.kb[nt * 16 + l16][32 + quad * 8];
    acc[nt] = __builtin_amdgcn_mfma_f32_16x16x32_bf16(a0, b0, acc[nt], 0, 0, 0);
    acc[nt] = __builtin_amdgcn_mfma_f32_16x16x32_bf16(a1, b1, acc[nt], 0, 0, 0);
  }

  // ---- self-mask + softmax ----
  int tqr[4];
#pragma unroll
  for (int r = 0; r < 4; r++) tqr[r] = sm.tk[w * 16 + quad * 4 + r];
  int tkc[8];
#pragma unroll
  for (int nt = 0; nt < 8; nt++) tkc[nt] = sm.tk[nt * 16 + l16];

#pragma unroll
  for (int nt = 0; nt < 8; nt++)
#pragma unroll
    for (int r = 0; r < 4; r++)
      if (tqr[r] == tkc[nt]) acc[nt][r] = -50000.0f;

  float rmax[4], lse[4], inv[4];
#pragma unroll
  for (int r = 0; r < 4; r++) {
    float m = acc[0][r];
#pragma unroll
    for (int nt = 1; nt < 8; nt++) m = fmaxf(m, acc[nt][r]);
    m = fmaxf(m, __shfl_xor(m, 1));
    m = fmaxf(m, __shfl_xor(m, 2));
    m = fmaxf(m, __shfl_xor(m, 4));
    m = fmaxf(m, __shfl_xor(m, 8));
    rmax[r] = m;
  }
#pragma unroll
  for (int r = 0; r < 4; r++) {
    float s = 0.f;
#pragma unroll
    for (int nt = 0; nt < 8; nt++) {
      const float e = __expf(acc[nt][r] - rmax[r]);
      acc[nt][r] = e;
      s += e;
    }
    s += __shfl_xor(s, 1);
    s += __shfl_xor(s, 2);
    s += __shfl_xor(s, 4);
    s += __shfl_xor(s, 8);
    inv[r] = 1.0f / s;
    lse[r] = __logf(s) + rmax[r];
  }

  if (l16 == 0) {
#pragma unroll
    for (int r = 0; r < 4; r++)
      lse_u[((size_t)b * SS + tqr[r]) * HH + h] = lse[r];
  }

  __syncthreads();   // all kb reads done -> safe to overwrite with p

  // ---- stage probs bf16, row-major p[qi][j], overlaid on kb ----
#pragma unroll
  for (int nt = 0; nt < 8; nt++)
#pragma unroll
    for (int r = 0; r < 4; r++)
      sm.kp.p[w * 16 + quad * 4 + r][nt * 16 + l16] = f2bf(acc[nt][r] * inv[r]);
  __syncthreads();

  // ---- PV as O^T = V^T * P^T ----
  f32x4 o[4];
#pragma unroll
  for (int nt = 0; nt < 4; nt++) o[nt] = (f32x4){0.f, 0.f, 0.f, 0.f};
#pragma unroll
  for (int kc = 0; kc < 4; kc++) {
    s16x8 av;
#pragma unroll
    for (int e = 0; e < 8; e++)
      av[e] = (short)sm.vs[kc * 32 + quad * 8 + e][w * 16 + l16];
#pragma unroll
    for (int nt = 0; nt < 4; nt++) {
      const s16x8 bp = *(const s16x8*)&sm.kp.p[nt * 16 + l16][kc * 32 + quad * 8];
      o[nt] = __builtin_amdgcn_mfma_f32_16x16x32_bf16(av, bp, o[nt], 0, 0, 0);
    }
  }

#pragma unroll
  for (int nt = 0; nt < 4; nt++) {
    const int t = sm.tk[nt * 16 + l16];
    s16x4 ov;
#pragma unroll
    for (int r = 0; r < 4; r++) ov[r] = (short)f2bf(o[nt][r]);
    unsigned short* dst =
        so + (((size_t)b * SS + t) * HH + h) * DD + w * 16 + quad * 4;
    *(s16x4*)dst = ov;
  }
}

// ---------------------------------------------------------------------------
// Kernel 4: streaming combine over hashes (R7, unchanged).
// ---------------------------------------------------------------------------
__global__ __launch_bounds__(256) void k_combine2(
    const unsigned short* __restrict__ so, const float* __restrict__ lse_u,
    float* __restrict__ out) {
  const size_t idx = (size_t)blockIdx.x * 256 + threadIdx.x;
  const int f = (int)(idx & 63);
  const size_t bt = idx >> 6;

  float l[HH];
#pragma unroll
  for (int h = 0; h < HH; h++) l[h] = lse_u[bt * HH + h];
  float m = l[0];
#pragma unroll
  for (int h = 1; h < HH; h++) m = fmaxf(m, l[h]);
  float den = 0.f, num = 0.f;
#pragma unroll
  for (int h = 0; h < HH; h++) {
    const float wgt = __expf(l[h] - m);
    den += wgt;
    num += wgt * bf2f(so[(bt * HH + h) * DD + f]);
  }
  out[idx] = num / den;
}

// ---------------------------------------------------------------------------
// Fallback-path hash (R8's fp32) + atomic attention (R1-proven).
// ---------------------------------------------------------------------------
__global__ __launch_bounds__(256, 2) void k_hash_f32(
    const float* __restrict__ qk, const float* __restrict__ rot,
    int* __restrict__ bucket_local, float* __restrict__ buckets_out,
    int* __restrict__ needy_list, int* __restrict__ needy_count) {
  __shared__ float lb[128 * 65];
  const int b = blockIdx.x;
  const int t0 = blockIdx.y * 128;
  const int tid = threadIdx.x;

  {
    const int row = tid >> 1, hf = (tid & 1) * 32;
    const float4* src =
        (const float4*)(qk + ((size_t)b * SS + t0 + row) * DD + hf);
    float* dst = &lb[row * 65 + hf];
#pragma unroll
    for (int g = 0; g < 8; g++) {
      const float4 vv = src[g];
      dst[g * 4 + 0] = vv.x; dst[g * 4 + 1] = vv.y;
      dst[g * 4 + 2] = vv.z; dst[g * 4 + 3] = vv.w;
    }
  }
  __syncthreads();

  const int w = tid >> 6;
  const int l = tid & 63;
  const int hb = __builtin_amdgcn_readfirstlane(w);

  for (int hp = 0; hp < 2; hp++) {
    const int h = hb + hp * 4;
    const float* rbase = rot + ((size_t)b * DD * HH + h) * NBH;
    const size_t rstride = HH * NBH;

    float acc0[NBH], acc1[NBH];
#pragma unroll
    for (int i = 0; i < NBH; i++) { acc0[i] = 0.f; acc1[i] = 0.f; }

    float4 bufA[8], bufB[8];
#pragma unroll
    for (int i4 = 0; i4 < 8; i4++) bufA[i4] = ((const float4*)rbase)[i4];

    for (int f = 0; f < DD; f += 2) {
      {
        const float4* r4 = (const float4*)(rbase + (size_t)(f + 1) * rstride);
#pragma unroll
        for (int i4 = 0; i4 < 8; i4++) bufB[i4] = r4[i4];
      }
      {
        const float q0 = lb[l * 65 + f];
        const float q1 = lb[(l + 64) * 65 + f];
#pragma unroll
        for (int i4 = 0; i4 < 8; i4++) {
          const float4 rv = bufA[i4];
          acc0[i4*4+0] = fmaf(q0, rv.x, acc0[i4*4+0]);
          acc0[i4*4+1] = fmaf(q0, rv.y, acc0[i4*4+1]);
          acc0[i4*4+2] = fmaf(q0, rv.z, acc0[i4*4+2]);
          acc0[i4*4+3] = fmaf(q0, rv.w, acc0[i4*4+3]);
          acc1[i4*4+0] = fmaf(q1, rv.x, acc1[i4*4+0]);
          acc1[i4*4+1] = fmaf(q1, rv.y, acc1[i4*4+1]);
          acc1[i4*4+2] = fmaf(q1, rv.z, acc1[i4*4+2]);
          acc1[i4*4+3] = fmaf(q1, rv.w, acc1[i4*4+3]);
        }
      }
      if (f + 2 < DD) {
        const float4* r4 = (const float4*)(rbase + (size_t)(f + 2) * rstride);
#pragma unroll
        for (int i4 = 0; i4 < 8; i4++) bufA[i4] = r4[i4];
      }
      {
        const float q0 = lb[l * 65 + f + 1];
        const float q1 = lb[(l + 64) * 65 + f + 1];
#pragma unroll
        for (int i4 = 0; i4 < 8; i4++) {
          const float4 rv = bufB[i4];
          acc0[i4*4+0] = fmaf(q0, rv.x, acc0[i4*4+0]);
          acc0[i4*4+1] = fmaf(q0, rv.y, acc0[i4*4+1]);
          acc0[i4*4+2] = fmaf(q0, rv.z, acc0[i4*4+2]);
          acc0[i4*4+3] = fmaf(q0, rv.w, acc0[i4*4+3]);
          acc1[i4*4+0] = fmaf(q1, rv.x, acc1[i4*4+0]);
          acc1[i4*4+1] = fmaf(q1, rv.y, acc1[i4*4+1]);
          acc1[i4*4+2] = fmaf(q1, rv.z, acc1[i4*4+2]);
          acc1[i4*4+3] = fmaf(q1, rv.w, acc1[i4*4+3]);
        }
      }
    }

#pragma unroll
    for (int tok = 0; tok < 2; tok++) {
      const float* acc = tok ? acc1 : acc0;
      float best = -3.0e38f, second = -3.0e38f;
      int bi = 0;
#pragma unroll
      for (int i = 0; i < 64; i++) {
        const float vv = (i < NBH) ? acc[i] : -acc[i - NBH];
        if (vv > best) { second = best; best = vv; bi = i; }
        else if (vv > second) { second = vv; }
      }
      const int t = t0 + tok * 64 + l;
      bucket_local[((size_t)b * HH + h) * SS + t] = bi;
      buckets_out[(size_t)b * (HH * SS) + (size_t)h * SS + t] =
          (float)(h * NB + bi);
      if (best - second <= MARGIN) {
        const int slot = atomicAdd(needy_count, 1);
        needy_list[slot] = (((b << 3) | h) << 12) | t;
      }
    }
  }
}

__global__ __launch_bounds__(256) void k_attn_atomic(
    const float* __restrict__ qk, const float* __restrict__ v,
    const int* __restrict__ sort_t, float* __restrict__ num,
    float* __restrict__ den) {
  const int blk = blockIdx.x;
  const int b = blk >> 9;
  const int c = blk & 511;
  const int h = c >> 6, cc = c & 63;
  const int cp = (c + 511) & 511;
  const int hp = cp >> 6, ccp = cp & 63;

  __shared__ union {
    struct {
      float qt[DD * 64];
      float kt[DD * 128];
      int   tq[64];
      int   tk[128];
      float nrm[128];
      float red[16 * 64];
      float rmax[64];
      float rsum[64];
    } a;
    struct {
      float pt[128 * 64];
      float vs[128 * 64];
    } p;
  } sm;

  const int tid = threadIdx.x;

  if (tid < 64)
    sm.a.tq[tid] = sort_t[((size_t)b * HH + h) * SS + cc * 64 + tid];
  if (tid >= 128) {
    const int j = tid - 128;
    const size_t src = (j < 64) ? (((size_t)b * HH + h) * SS + cc * 64 + j)
                                : (((size_t)b * HH + hp) * SS + ccp * 64 + (j - 64));
    sm.a.tk[j] = sort_t[src];
  }
  if (tid >= 64 && tid < 192) sm.a.nrm[tid - 64] = 0.f;
  __syncthreads();

  {
    const int qi = tid >> 2, qq = tid & 3;
    const float4* qsrc =
        (const float4*)(qk + ((size_t)b * SS + sm.a.tq[qi]) * DD) + qq * 4;
#pragma unroll
    for (int k4 = 0; k4 < 4; k4++) {
      float4 val = qsrc[k4];
      const int f = qq * 16 + k4 * 4;
      sm.a.qt[(f + 0) * 64 + qi] = val.x;
      sm.a.qt[(f + 1) * 64 + qi] = val.y;
      sm.a.qt[(f + 2) * 64 + qi] = val.z;
      sm.a.qt[(f + 3) * 64 + qi] = val.w;
    }
    const int j = tid >> 1, hhf = tid & 1;
    const float4* ksrc =
        (const float4*)(qk + ((size_t)b * SS + sm.a.tk[j]) * DD) + hhf * 8;
    float ss = 0.f;
#pragma unroll
    for (int k4 = 0; k4 < 8; k4++) {
      float4 val = ksrc[k4];
      const int f = hhf * 32 + k4 * 4;
      sm.a.kt[(f + 0) * 128 + j] = val.x;
      sm.a.kt[(f + 1) * 128 + j] = val.y;
      sm.a.kt[(f + 2) * 128 + j] = val.z;
      sm.a.kt[(f + 3) * 128 + j] = val.w;
      ss += val.x * val.x + val.y * val.y + val.z * val.z + val.w * val.w;
    }
    atomicAdd(&sm.a.nrm[j], ss);
  }
  __syncthreads();
  if (tid < 128) {
    const float n = sqrtf(sm.a.nrm[tid]) + 1e-6f;
    sm.a.nrm[tid] = 0.125f / n;
  }
  float4 vreg[8];
  {
    const int j = tid >> 1, hhf = tid & 1;
    const float4* vsrc =
        (const float4*)(v + ((size_t)b * SS + sm.a.tk[j]) * DD) + hhf * 8;
#pragma unroll
    for (int k4 = 0; k4 < 8; k4++) vreg[k4] = vsrc[k4];
  }
  __syncthreads();

  const int qi0 = (tid & 15) * 4;
  const int j0g = (tid >> 4) * 8;
  const int kg = tid >> 4;
  float acc[4][8];
#pragma unroll
  for (int i = 0; i < 4; i++)
#pragma unroll
    for (int j = 0; j < 8; j++) acc[i][j] = 0.f;

#pragma unroll 8
  for (int f = 0; f < DD; f++) {
    float4 qv = *(const float4*)&sm.a.qt[f * 64 + qi0];
    float4 k0 = *(const float4*)&sm.a.kt[f * 128 + j0g];
    float4 k1 = *(const float4*)&sm.a.kt[f * 128 + j0g + 4];
    float qa[4] = {qv.x, qv.y, qv.z, qv.w};
    float ka[8] = {k0.x, k0.y, k0.z, k0.w, k1.x, k1.y, k1.z, k1.w};
#pragma unroll
    for (int i = 0; i < 4; i++)
#pragma unroll
      for (int j = 0; j < 8; j++) acc[i][j] = fmaf(qa[i], ka[j], acc[i][j]);
  }

  int tqr[4];
#pragma unroll
  for (int i = 0; i < 4; i++) tqr[i] = sm.a.tq[qi0 + i];
  int tkr[8]; float scl[8];
#pragma unroll
  for (int j = 0; j < 8; j++) {
    tkr[j] = sm.a.tk[j0g + j];
    scl[j] = sm.a.nrm[j0g + j];
  }
#pragma unroll
  for (int i = 0; i < 4; i++)
#pragma unroll
    for (int j = 0; j < 8; j++) {
      const float dv = acc[i][j] * scl[j];
      acc[i][j] = (tqr[i] == tkr[j]) ? -50000.0f : dv;
    }

  float pmax[4];
#pragma unroll
  for (int i = 0; i < 4; i++) {
    float m = acc[i][0];
#pragma unroll
    for (int j = 1; j < 8; j++) m = fmaxf(m, acc[i][j]);
    pmax[i] = m;
  }
#pragma unroll
  for (int i = 0; i < 4; i++) sm.a.red[kg * 64 + qi0 + i] = pmax[i];
  __syncthreads();
  if (tid < 64) {
    float m = -3.0e38f;
#pragma unroll
    for (int g = 0; g < 16; g++) m = fmaxf(m, sm.a.red[g * 64 + tid]);
    sm.a.rmax[tid] = m;
  }
  __syncthreads();
  float psum[4];
#pragma unroll
  for (int i = 0; i < 4; i++) {
    const float rm = sm.a.rmax[qi0 + i];
    float s = 0.f;
#pragma unroll
    for (int j = 0; j < 8; j++) {
      const float e = __expf(acc[i][j] - rm);
      acc[i][j] = e;
      s += e;
    }
    psum[i] = s;
  }
#pragma unroll
  for (int i = 0; i < 4; i++) sm.a.red[kg * 64 + qi0 + i] = psum[i];
  __syncthreads();
  if (tid < 64) {
    float s = 0.f;
#pragma unroll
    for (int g = 0; g < 16; g++) s += sm.a.red[g * 64 + tid];
    sm.a.rsum[tid] = s;
  }
  __syncthreads();
  float lse[4], isum[4];
#pragma unroll
  for (int i = 0; i < 4; i++) {
    const float rm = sm.a.rmax[qi0 + i];
    const float s = sm.a.rsum[qi0 + i];
    isum[i] = 1.0f / s;
    lse[i] = __logf(s) + rm;
  }
  __syncthreads();

#pragma unroll
  for (int j = 0; j < 8; j++)
#pragma unroll
    for (int i = 0; i < 4; i++)
      sm.p.pt[(j0g + j) * 64 + qi0 + i] = acc[i][j] * isum[i];
  {
    const int j = tid >> 1, hhf = tid & 1;
#pragma unroll
    for (int k4 = 0; k4 < 8; k4++)
      *(float4*)&sm.p.vs[j * 64 + hhf * 32 + k4 * 4] = vreg[k4];
  }
  __syncthreads();

  const int f0 = (tid >> 4) * 4;
  float o[4][4];
#pragma unroll
  for (int i = 0; i < 4; i++)
#pragma unroll
    for (int j = 0; j < 4; j++) o[i][j] = 0.f;

#pragma unroll 8
  for (int j = 0; j < 128; j++) {
    float4 pv = *(const float4*)&sm.p.pt[j * 64 + qi0];
    float4 vv = *(const float4*)&sm.p.vs[j * 64 + f0];
    float pa[4] = {pv.x, pv.y, pv.z, pv.w};
    float va[4] = {vv.x, vv.y, vv.z, vv.w};
#pragma unroll
    for (int i = 0; i < 4; i++)
#pragma unroll
      for (int j2 = 0; j2 < 4; j2++) o[i][j2] = fmaf(pa[i], va[j2], o[i][j2]);
  }

#pragma unroll
  for (int i = 0; i < 4; i++) {
    const float w = __expf(lse[i]);
    float* dst = num + ((size_t)b * SS + tqr[i]) * DD + f0;
#pragma unroll
    for (int j = 0; j < 4; j++) atomicAdd(dst + j, o[i][j] * w);
    if (kg == 0) atomicAdd(den + (size_t)b * SS + tqr[i], w);
  }
}

__global__ __launch_bounds__(256) void k_final(float* __restrict__ o,
                                               const float* __restrict__ den) {
  const size_t i = (size_t)blockIdx.x * 256 + threadIdx.x;
  o[i] = o[i] / den[i >> 6];
}

extern "C" void kernel_launch(void* const* d_in, const int* in_sizes, int n_in,
                              void* d_out, int out_size, void* d_ws,
                              size_t ws_size, hipStream_t stream) {
  const float* qk  = (const float*)d_in[0];
  const float* v   = (const float*)d_in[1];
  const float* rot = (const float*)d_in[2];

  float* out_attn = (float*)d_out;                      // B*S*D floats
  float* buckets_out = out_attn + (size_t)BB * SS * DD; // B*H*S floats

  const size_t BHS = (size_t)BB * HH * SS;              // 524288
  const size_t BSD = (size_t)BB * SS * DD;              // 4194304
  const size_t RT  = (size_t)BB * HH * 32 * DD;         // 262144
  int* bucket_local = (int*)d_ws;
  int* sort_t = bucket_local + BHS;                     // doubles as needy_list
  int* ipos = sort_t + BHS;                             // ipos[0] = needy_count
  float* lse_u = (float*)(ipos + BHS);                  // [b][t][h]
  unsigned short* qb16 = (unsigned short*)(lse_u + BHS);
  unsigned short* kb16 = qb16 + BSD;
  unsigned short* vb16 = kb16 + BSD;
  unsigned short* so_u = vb16 + BSD;                    // [b][t][h][f] bf16
  unsigned short* rTh = so_u + BHS * DD;
  unsigned short* rTl = rTh + RT;

  const size_t NEED2 =
      4 * BHS * 4 + 3 * BSD * 2 + BHS * DD * 2 + 2 * RT * 2;  // ~101.7 MB

  if (ws_size >= NEED2) {
    k_conv<<<2 * BB * SS * 4 / 256, 256, 0, stream>>>(qk, v, qb16, kb16, vb16);
    k_rotT<<<BB, 256, 0, stream>>>(rot, rTh, rTl, ipos);   // also zeroes needy_count
    k_hash_mfma<<<dim3(BB, SS / 128), 256, 0, stream>>>(
        qk, rTh, rTl, bucket_local, buckets_out, sort_t, ipos);
    k_hash_fix<<<256, 256, 0, stream>>>(qk, rot, sort_t, ipos, bucket_local,
                                        buckets_out);
    k_sort<<<BB * HH, 256, 0, stream>>>(bucket_local, sort_t, ipos);
    k_attn2<<<BB * NCH, 256, 0, stream>>>(qb16, kb16, vb16, sort_t, so_u, lse_u);
    k_combine2<<<(BB * SS * DD) / 256, 256, 0, stream>>>(so_u, lse_u, out_attn);
  } else {
    float* den = (float*)(sort_t + 2 * BHS);
    hipMemsetAsync(out_attn, 0, (size_t)BB * SS * DD * sizeof(float), stream);
    hipMemsetAsync(den, 0, (size_t)BB * SS * sizeof(float), stream);
    hipMemsetAsync(ipos, 0, sizeof(int), stream);
    k_hash_f32<<<dim3(BB, SS / 128), 256, 0, stream>>>(
        qk, rot, bucket_local, buckets_out, sort_t, ipos);
    k_hash_fix<<<256, 256, 0, stream>>>(qk, rot, sort_t, ipos, bucket_local,
                                        buckets_out);
    k_sort<<<BB * HH, 256, 0, stream>>>(bucket_local, sort_t, ipos);
    k_attn_atomic<<<BB * NCH, 256, 0, stream>>>(qk, v, sort_t, out_attn, den);
    k_final<<<(BB * SS * DD) / 256, 256, 0, stream>>>(out_attn, den);
  }
}